// Round 14
// baseline (37.246 us; speedup 1.0000x reference)
//
#include <hip/hip_runtime.h>

#define LEAKY(x) ((x) > 0.0f ? (x) : 0.01f * (x))

// ws float layout
#define GP_F    672     // GP inside consts [0..2208)
#define APE     2208    // ap_enc 4096
#define UEE     6304    // ue_enc 16384
#define EAE     22688   // ea_enc 49152
#define G_F     71840   // g 16384

__device__ __forceinline__ float2 cmul(float2 a, float2 b) {
  return make_float2(fmaf(a.x, b.x, -a.y * b.y), fmaf(a.x, b.y, a.y * b.x));
}
__device__ __forceinline__ float2 cmulc(float2 a, float2 b) {  // conj(a)*b
  return make_float2(fmaf(a.x, b.x, a.y * b.y), fmaf(a.x, b.y, -a.y * b.x));
}
__device__ __forceinline__ float2 cadd(float2 a, float2 b) {
  return make_float2(a.x + b.x, a.y + b.y);
}
__device__ __forceinline__ float2 csub(float2 a, float2 b) {
  return make_float2(a.x - b.x, a.y - b.y);
}
__device__ __forceinline__ void swap2(float2& a, float2& b) {
  float2 t = a; a = b; b = t;
}

struct C2 { float2 e[4]; };

__device__ C2 cmm(const C2& A, const C2& B) {
  C2 R;
  #pragma unroll
  for (int r = 0; r < 2; ++r)
    #pragma unroll
    for (int c = 0; c < 2; ++c)
      R.e[r*2+c] = cadd(cmul(A.e[r*2+0], B.e[0*2+c]), cmul(A.e[r*2+1], B.e[1*2+c]));
  return R;
}
__device__ C2 gRX(float t) {
  float s = __sinf(0.5f*t), c = __cosf(0.5f*t);
  C2 M;
  M.e[0] = make_float2(c, 0.f);  M.e[1] = make_float2(0.f, -s);
  M.e[2] = make_float2(0.f, -s); M.e[3] = make_float2(c, 0.f);
  return M;
}
__device__ C2 gRY(float t) {
  float s = __sinf(0.5f*t), c = __cosf(0.5f*t);
  C2 M;
  M.e[0] = make_float2(c, 0.f);  M.e[1] = make_float2(-s, 0.f);
  M.e[2] = make_float2(s, 0.f);  M.e[3] = make_float2(c, 0.f);
  return M;
}
__device__ C2 gRZ(float t) {
  float s = __sinf(0.5f*t), c = __cosf(0.5f*t);
  C2 M;
  M.e[0] = make_float2(c, -s);    M.e[1] = make_float2(0.f, 0.f);
  M.e[2] = make_float2(0.f, 0.f); M.e[3] = make_float2(c, s);
  return M;
}
__device__ C2 gROT(float phi, float th, float om) {
  return cmm(cmm(gRZ(om), gRY(th)), gRZ(phi));
}

// row-per-thread 2-layer MLP; W1 transposed in LDS, all reads wave-uniform (broadcast).
template<int D>
__device__ __forceinline__ void encode_block(
    const float* __restrict__ x, int r,
    const float* __restrict__ W1, const float* __restrict__ b1,
    const float* __restrict__ W2, const float* __restrict__ b2,
    float* w1t, float* b1s, float* w2s, float* __restrict__ outp, int tid) {
  #pragma unroll
  for (int i = 0; i < D/2; ++i) {
    const int idx = i*256 + tid;
    const float v = W1[idx];
    w1t[(idx & 127)*D + (idx >> 7)] = v;
  }
  if (tid < 128) b1s[tid] = b1[tid];
  w2s[tid] = W2[tid];
  __syncthreads();

  float xv[D];
  *(float4*)xv = *(const float4*)(x + r*D);
  if (D == 8) *(float4*)(xv + 4) = *(const float4*)(x + r*D + 4);

  float o0 = 0.f, o1 = 0.f;
  #pragma unroll 4
  for (int j = 0; j < 128; ++j) {
    float h = b1s[j];
    #pragma unroll
    for (int k = 0; k < D; k += 4) {
      const float4 w = *(const float4*)&w1t[j*D + k];
      h = fmaf(xv[k],   w.x, h);
      h = fmaf(xv[k+1], w.y, h);
      h = fmaf(xv[k+2], w.z, h);
      h = fmaf(xv[k+3], w.w, h);
    }
    h = LEAKY(h);
    const float2 w2 = *(const float2*)&w2s[j*2];
    o0 = fmaf(h, w2.x, o0);
    o1 = fmaf(h, w2.y, o1);
  }
  *(float2*)(outp + r*2) = make_float2(o0 + b2[0], o1 + b2[1]);
}

// blocks 0..135: encoders (256 rows/block, row-per-thread). block 136: gate algebra.
__global__ __launch_bounds__(256) void enc_kernel(
    const float* __restrict__ x_ue, const float* __restrict__ x_ap,
    const float* __restrict__ edge_attr,
    const float* __restrict__ Wn1u, const float* __restrict__ bn1u,
    const float* __restrict__ Wn2u, const float* __restrict__ bn2u,
    const float* __restrict__ Wn1a, const float* __restrict__ bn1a,
    const float* __restrict__ Wn2a, const float* __restrict__ bn2a,
    const float* __restrict__ We1,  const float* __restrict__ be1,
    const float* __restrict__ We2,  const float* __restrict__ be2,
    const float* __restrict__ strongp, const float* __restrict__ initsp,
    const float* __restrict__ updatep, float* __restrict__ ws) {
  __shared__ __align__(16) float w1t[1024];
  __shared__ float b1s[128];
  __shared__ __align__(8) float w2s[256];
  __shared__ float2 U2s[16][17];
  const int bi = blockIdx.x, tid = threadIdx.x;

  if (bi < 32) {
    encode_block<8>(x_ue, bi*256 + tid, Wn1u, bn1u, Wn2u, bn2u,
                    w1t, b1s, w2s, ws + UEE, tid);
    return;
  } else if (bi < 40) {
    encode_block<8>(x_ap, (bi-32)*256 + tid, Wn1a, bn1a, Wn2a, bn2a,
                    w1t, b1s, w2s, ws + APE, tid);
    return;
  } else if (bi < 136) {
    encode_block<4>(edge_attr, (bi-40)*256 + tid, We1, be1, We2, be2,
                    w1t, b1s, w2s, ws + EAE, tid);
    return;
  }

  // ---- gate algebra (block 136) ----
  if (tid < 48) {
    // U_k (k=tid>>4), column col=tid&15. bit masks: wire3=8, nb=4, w7=2, w8=1.
    const int k = tid >> 4, col = tid & 15;
    float2 u[16];
    #pragma unroll
    for (int r = 0; r < 16; ++r) u[r] = make_float2(r == col ? 1.f : 0.f, 0.f);
    #pragma unroll
    for (int l = 0; l < 2; ++l) {
      #pragma unroll
      for (int j = 0; j < 4; ++j) {
        const float* p = updatep + k*24 + l*12 + j*3;
        C2 U = gROT(p[0], p[1], p[2]);
        const int m = 8 >> j;
        #pragma unroll
        for (int r = 0; r < 16; ++r)
          if (!(r & m)) {
            float2 a0 = u[r], a1 = u[r | m];
            u[r]     = cadd(cmul(U.e[0], a0), cmul(U.e[1], a1));
            u[r | m] = cadd(cmul(U.e[2], a0), cmul(U.e[3], a1));
          }
      }
      #pragma unroll
      for (int j = 0; j < 4; ++j) {
        const int mc = 8 >> j;
        const int mt0[4] = {4, 2, 1, 8};
        const int mt1[4] = {2, 1, 8, 4};
        const int mt = (l == 0) ? mt0[j] : mt1[j];
        #pragma unroll
        for (int r = 0; r < 16; ++r)
          if ((r & mc) && !(r & mt)) swap2(u[r], u[r | mt]);
      }
    }
    if (k == 0) {
      if (!(col & 3)) {
        const int jc = col >> 2;
        #pragma unroll
        for (int r = 0; r < 16; ++r) {
          ws[32 + (jc*16 + r)*2 + 0] = u[r].x;
          ws[32 + (jc*16 + r)*2 + 1] = u[r].y;
        }
      }
    } else if (k == 1) {
      // paired layout: U1tp[col][rp] = (U1[r][col], U1[r+4][col]), r = (rp&3)|((rp&4)<<1)
      #pragma unroll
      for (int rp = 0; rp < 8; ++rp) {
        const int r = (rp & 3) | ((rp & 4) << 1);
        ws[160 + (col*8 + rp)*4 + 0] = u[r].x;
        ws[160 + (col*8 + rp)*4 + 1] = u[r].y;
        ws[160 + (col*8 + rp)*4 + 2] = u[r+4].x;
        ws[160 + (col*8 + rp)*4 + 3] = u[r+4].y;
      }
    } else {
      #pragma unroll
      for (int r = 0; r < 16; ++r) U2s[col][r] = u[r];   // U2s[q][t] = U2[t][q]
    }
  }
  if (tid == 48) {
    // M_edge 4x4 (basis (b_e<<1)|b_nb)
    float2 M[4][4];
    #pragma unroll
    for (int r = 0; r < 4; ++r)
      #pragma unroll
      for (int c = 0; c < 4; ++c)
        M[r][c] = make_float2(r == c ? 1.f : 0.f, 0.f);
    auto rowpair = [&](int r0, int r1, C2 U) {
      #pragma unroll
      for (int c = 0; c < 4; ++c) {
        float2 a0 = M[r0][c], a1 = M[r1][c];
        M[r0][c] = cadd(cmul(U.e[0], a0), cmul(U.e[1], a1));
        M[r1][c] = cadd(cmul(U.e[2], a0), cmul(U.e[3], a1));
      }
    };
    auto rowswap = [&](int r0, int r1) {
      #pragma unroll
      for (int c = 0; c < 4; ++c) swap2(M[r0][c], M[r1][c]);
    };
    rowpair(1, 3, gRX(initsp[0]));
    rowpair(2, 3, gRY(initsp[1]));
    #pragma unroll
    for (int l = 0; l < 2; ++l) {
      C2 Re = gROT(strongp[l*6+0], strongp[l*6+1], strongp[l*6+2]);
      C2 Rn = gROT(strongp[l*6+3], strongp[l*6+4], strongp[l*6+5]);
      rowpair(0, 2, Re); rowpair(1, 3, Re);
      rowpair(0, 1, Rn); rowpair(2, 3, Rn);
      rowswap(2, 3);
      rowswap(1, 3);
    }
    #pragma unroll
    for (int r = 0; r < 4; ++r)
      #pragma unroll
      for (int c = 0; c < 4; ++c) {
        ws[(r*4 + c)*2 + 0] = M[r][c].x;
        ws[(r*4 + c)*2 + 1] = M[r][c].y;
      }
  }
  __syncthreads();
  {
    // GP: 256 threads, one (c,cp,n,np) each, 3 wires.
    const int c = tid >> 5, cp = (tid >> 2) & 7, n = (tid >> 1) & 1, np = tid & 1;
    const int q  = ((c  & 4) << 1) | (n  << 2) | (c  & 3);
    const int qp = ((cp & 4) << 1) | (np << 2) | (cp & 3);
    float2 g3 = make_float2(0,0), g7 = g3, g8 = g3;
    #pragma unroll
    for (int t = 0; t < 16; ++t) {
      float2 pr = cmulc(U2s[q][t], U2s[qp][t]);
      g3 = (t & 8) ? csub(g3, pr) : cadd(g3, pr);
      g7 = (t & 2) ? csub(g7, pr) : cadd(g7, pr);
      g8 = (t & 1) ? csub(g8, pr) : cadd(g8, pr);
    }
    const int idx = (c*2 + n)*16 + (cp*2 + np);
    ws[GP_F + (0*256 + idx)*2 + 0] = g3.x;
    ws[GP_F + (0*256 + idx)*2 + 1] = g3.y;
    ws[GP_F + (1*256 + idx)*2 + 0] = g7.x;
    ws[GP_F + (1*256 + idx)*2 + 1] = g7.y;
    ws[GP_F + (2*256 + idx)*2 + 0] = g8.x;
    ws[GP_F + (2*256 + idx)*2 + 1] = g8.y;
  }
}

// 4 UEs/block (1/wave). Consts staged in LDS; enc values read from ws.
__global__ __launch_bounds__(256) void circuit_kernel(
    float* __restrict__ ws, const int* __restrict__ esrc,
    const float* __restrict__ Wu1, const float* __restrict__ bu1,
    const float* __restrict__ Wu2, const float* __restrict__ bu2,
    const float* __restrict__ lng, const float* __restrict__ lnb) {
  __shared__ __align__(16) float2 cst[1104];   // ME 16 | U0c 64 | U1tp 256 | GP 768
  __shared__ __align__(16) float2 pr_s[4][3][4];
  __shared__ __align__(16) float2 psi0[4][2][16];
  __shared__ __align__(16) float4 psi2p[4][8][8];  // [wv][ibr][rp] = (z[r], z[r+4])
  const int tid = threadIdx.x, wv = tid >> 6, lane = tid & 63;
  const int u = blockIdx.x*4 + wv;

  // ---- prefetch per-UE inputs (overlaps staging) ----
  const float2 ue_ab = *(const float2*)(ws + UEE + u*2);
  float2 eab_r = make_float2(0.f, 0.f), nab_r = make_float2(0.f, 0.f);
  if (lane < 12) {
    const int i = lane >> 2;
    eab_r = *(const float2*)(ws + EAE + (u*3 + i)*2);
    const int s = esrc[u*3 + i];
    nab_r = *(const float2*)(ws + APE + s*2);
  }

  {
    const float4* s4 = (const float4*)ws;
    float4* d4 = (float4*)cst;
    #pragma unroll
    for (int i = tid; i < 552; i += 256) d4[i] = s4[i];
  }
  __syncthreads();

  const float2* MEl  = cst;
  const float2* U0cl = cst + 16;
  const float4* U1tp = (const float4*)(cst + 80);   // [q][rp]
  const float4* GP4  = (const float4*)(cst + 336);  // paired GP

  auto mkv = [](float aa, float bb, float2& v0, float2& v1) {
    const float sa = __sinf(0.5f*aa), ca = __cosf(0.5f*aa);
    const float sb = __sinf(0.5f*bb), cb = __cosf(0.5f*bb);
    v0 = make_float2(cb*ca, -sb*ca);
    v1 = make_float2(sa*sb, -sa*cb);
  };
  float2 t0, t1;
  mkv(ue_ab.x, ue_ab.y, t0, t1);

  // ---- pairs (lanes 0..11): i = lane>>2, r = lane&3 ----
  if (lane < 12) {
    const int r = lane & 3;
    float2 e0, e1, n0, n1;
    mkv(eab_r.x, eab_r.y, e0, e1);
    mkv(nab_r.x, nab_r.y, n0, n1);
    float2 in4[4] = {cmul(e0,n0), cmul(e0,n1), cmul(e1,n0), cmul(e1,n1)};
    float2 acc = make_float2(0.f, 0.f);
    #pragma unroll
    for (int cc = 0; cc < 4; ++cc) acc = cadd(acc, cmul(MEl[r*4 + cc], in4[cc]));
    pr_s[wv][lane >> 2][r] = acc;
  }

  // ---- block0: psi0 (lanes 0..31) ----
  if (lane < 32) {
    const int b = lane >> 4, row = lane & 15;
    float2 acc = make_float2(0.f, 0.f);
    #pragma unroll
    for (int j = 0; j < 4; ++j) {
      const float2 phi = pr_s[wv][0][(b << 1) | (j & 1)];
      const float2 coef = cmul((j >> 1) ? t1 : t0, phi);
      acc = cadd(acc, cmul(U0cl[j*16 + row], coef));
    }
    psi0[wv][b][row] = acc;
  }

  // ---- block1: psi2 (all lanes, rows (r, r+4) per lane) ----
  {
    const int ibr = lane >> 3, rp = lane & 7;
    const int db = ibr >> 2, da = (ibr >> 1) & 1, dbp = ibr & 1;
    const float2 f10 = pr_s[wv][1][(dbp << 1) | 0];
    const float2 f11 = pr_s[wv][1][(dbp << 1) | 1];
    float2 chi[8];
    {
      const float4 a0 = *(const float4*)&psi0[wv][db][da*4 + 0];
      const float4 a1 = *(const float4*)&psi0[wv][db][da*4 + 2];
      const float4 a2 = *(const float4*)&psi0[wv][db][8 + da*4 + 0];
      const float4 a3 = *(const float4*)&psi0[wv][db][8 + da*4 + 2];
      chi[0] = make_float2(a0.x, a0.y); chi[1] = make_float2(a0.z, a0.w);
      chi[2] = make_float2(a1.x, a1.y); chi[3] = make_float2(a1.z, a1.w);
      chi[4] = make_float2(a2.x, a2.y); chi[5] = make_float2(a2.z, a2.w);
      chi[6] = make_float2(a3.x, a3.y); chi[7] = make_float2(a3.z, a3.w);
    }
    float2 q0 = make_float2(0.f, 0.f), q1 = q0;
    #pragma unroll
    for (int q = 0; q < 16; ++q) {
      const int cc = ((q >> 3) << 2) | (q & 3);
      const float2 xq = cmul(chi[cc], (q & 4) ? f11 : f10);
      const float4 uf = U1tp[q*8 + rp];
      const float2 u_lo = make_float2(uf.x, uf.y);
      const float2 u_hi = make_float2(uf.z, uf.w);
      q0 = cadd(q0, cmul(u_lo, xq));
      q1 = cadd(q1, cmul(u_hi, xq));
    }
    psi2p[wv][ibr][rp] = make_float4(q0.x, q0.y, q1.x, q1.y);
  }

  // ---- R[c,cp] ----
  const int c = lane >> 3, cp = lane & 7;
  float2 R = make_float2(0.f, 0.f);
  #pragma unroll
  for (int br = 0; br < 8; ++br) {
    const float4 Z1 = psi2p[wv][br][c];
    const float4 Z2 = psi2p[wv][br][cp];
    R.x += Z1.x*Z2.x + Z1.y*Z2.y + Z1.z*Z2.z + Z1.w*Z2.w;
    R.y += Z1.y*Z2.x - Z1.x*Z2.y + Z1.w*Z2.z - Z1.z*Z2.w;
  }

  // ---- rho2, K_w, ev ----
  const float4 f2a = *(const float4*)&pr_s[wv][2][0];
  const float4 f2b = *(const float4*)&pr_s[wv][2][2];
  const float2 f20 = make_float2(f2a.x, f2a.y), f21 = make_float2(f2a.z, f2a.w);
  const float2 f22 = make_float2(f2b.x, f2b.y), f23 = make_float2(f2b.z, f2b.w);
  const float2 rho00 = make_float2(f20.x*f20.x + f20.y*f20.y + f22.x*f22.x + f22.y*f22.y, 0.f);
  const float2 rho11 = make_float2(f21.x*f21.x + f21.y*f21.y + f23.x*f23.x + f23.y*f23.y, 0.f);
  const float2 rho01 = make_float2(fmaf(f20.x,f21.x,f20.y*f21.y) + fmaf(f22.x,f23.x,f22.y*f23.y),
                                   (f20.y*f21.x - f20.x*f21.y) + (f22.y*f23.x - f22.x*f23.y));
  const float2 rho10 = make_float2(rho01.x, -rho01.y);

  float ev0, ev1, ev2;
  {
    const int base4 = c*16 + cp;   // float4 index
    #pragma unroll
    for (int w = 0; w < 3; ++w) {
      const float4 Ga = GP4[w*128 + base4];       // (g00, g01)
      const float4 Gb = GP4[w*128 + base4 + 8];   // (g10, g11)
      const float2 g00 = make_float2(Ga.x, Ga.y), g01 = make_float2(Ga.z, Ga.w);
      const float2 g10 = make_float2(Gb.x, Gb.y), g11 = make_float2(Gb.z, Gb.w);
      float2 K = cmul(g00, rho00);
      K = cadd(K, cmul(g01, rho10));
      K = cadd(K, cmul(g10, rho01));
      K = cadd(K, cmul(g11, rho11));
      const float e = K.x*R.x + K.y*R.y;
      if (w == 0) ev0 = e; else if (w == 1) ev1 = e; else ev2 = e;
    }
  }
  #pragma unroll
  for (int o = 32; o; o >>= 1) {
    ev0 += __shfl_xor(ev0, o);
    ev1 += __shfl_xor(ev1, o);
    ev2 += __shfl_xor(ev2, o);
  }

  // ---- Wu MLP + residual + LN -> g ----
  const int j1 = lane, j2 = lane + 64;
  const float in5[5] = {ue_ab.x, ue_ab.y, ev0, ev1, ev2};
  float h1 = bu1[j1], h2 = bu1[j2];
  #pragma unroll
  for (int k = 0; k < 5; ++k) {
    h1 = fmaf(in5[k], Wu1[k*128 + j1], h1);
    h2 = fmaf(in5[k], Wu1[k*128 + j2], h2);
  }
  h1 = LEAKY(h1); h2 = LEAKY(h2);
  const float2 wu2a = *(const float2*)(Wu2 + j1*2);
  const float2 wu2b = *(const float2*)(Wu2 + j2*2);
  float p0 = fmaf(h1, wu2a.x, h2*wu2b.x);
  float p1 = fmaf(h1, wu2a.y, h2*wu2b.y);
  #pragma unroll
  for (int o = 32; o; o >>= 1) { p0 += __shfl_xor(p0, o); p1 += __shfl_xor(p1, o); }
  if (lane == 0) {
    const float hh0 = ue_ab.x + p0 + bu2[0];
    const float hh1 = ue_ab.y + p1 + bu2[1];
    const float mu = 0.5f*(hh0 + hh1);
    const float dd = hh0 - mu;
    const float inv = rsqrtf(dd*dd + 1e-5f);
    const float g0 =  dd*inv*lng[0] + lnb[0];
    const float g1 = -dd*inv*lng[1] + lnb[1];
    *(float2*)(ws + G_F + u*2) = make_float2(g0, g1);
  }
}

// head GEMM: 64 rows/block, thread tile 4 rows x 8 cols, act transposed in LDS.
__global__ __launch_bounds__(256) void head_kernel(
    const float* __restrict__ g,
    const float* __restrict__ Wf1, const float* __restrict__ bf1,
    const float* __restrict__ Wf2, const float* __restrict__ bf2,
    const float* __restrict__ Wf3, const float* __restrict__ bf3,
    float* __restrict__ out) {
  __shared__ __align__(16) float act_t[128][64];   // [j][row], 32 KB
  const int tid = threadIdx.x;
  const int r0 = blockIdx.x * 64;
  const int wv = tid >> 6;

  // ---- phase 1: act_t[j][row] = leaky(g@Wf1 + bf1), j = p*4 + wv, row = tid&63
  {
    const int row = tid & 63;
    const float2 gv = *(const float2*)(g + (r0 + row)*2);
    #pragma unroll
    for (int p = 0; p < 32; ++p) {
      const int j = p*4 + wv;
      act_t[j][row] = LEAKY(fmaf(gv.x, Wf1[j], fmaf(gv.y, Wf1[128 + j], bf1[j])));
    }
  }
  __syncthreads();

  // ---- phase 2: GEMM. cg = tid&15 (8 cols each), rg = tid>>4 (4 rows each).
  const int cg = tid & 15, rg = tid >> 4;
  float acc[4][8];
  {
    const float4 b0 = *(const float4*)(bf2 + cg*8);
    const float4 b1 = *(const float4*)(bf2 + cg*8 + 4);
    #pragma unroll
    for (int r = 0; r < 4; ++r) {
      acc[r][0]=b0.x; acc[r][1]=b0.y; acc[r][2]=b0.z; acc[r][3]=b0.w;
      acc[r][4]=b1.x; acc[r][5]=b1.y; acc[r][6]=b1.z; acc[r][7]=b1.w;
    }
  }
  #pragma unroll 4
  for (int k = 0; k < 128; ++k) {
    const float4 a4 = *(const float4*)&act_t[k][rg*4];
    const float4 w0 = *(const float4*)(Wf2 + k*128 + cg*8);
    const float4 w1 = *(const float4*)(Wf2 + k*128 + cg*8 + 4);
    const float av[4] = {a4.x, a4.y, a4.z, a4.w};
    #pragma unroll
    for (int r = 0; r < 4; ++r) {
      acc[r][0] = fmaf(av[r], w0.x, acc[r][0]);
      acc[r][1] = fmaf(av[r], w0.y, acc[r][1]);
      acc[r][2] = fmaf(av[r], w0.z, acc[r][2]);
      acc[r][3] = fmaf(av[r], w0.w, acc[r][3]);
      acc[r][4] = fmaf(av[r], w1.x, acc[r][4]);
      acc[r][5] = fmaf(av[r], w1.y, acc[r][5]);
      acc[r][6] = fmaf(av[r], w1.z, acc[r][6]);
      acc[r][7] = fmaf(av[r], w1.w, acc[r][7]);
    }
  }

  // ---- epilogue: leaky, @Wf3, reduce over cg, sigmoid
  float w3x[8], w3y[8];
  #pragma unroll
  for (int c = 0; c < 8; ++c) {
    const float2 w3 = *(const float2*)(Wf3 + (cg*8 + c)*2);
    w3x[c] = w3.x; w3y[c] = w3.y;
  }
  float p0[4], p1[4];
  #pragma unroll
  for (int r = 0; r < 4; ++r) {
    float s0 = 0.f, s1 = 0.f;
    #pragma unroll
    for (int c = 0; c < 8; ++c) {
      const float v = LEAKY(acc[r][c]);
      s0 = fmaf(v, w3x[c], s0);
      s1 = fmaf(v, w3y[c], s1);
    }
    p0[r] = s0; p1[r] = s1;
  }
  #pragma unroll
  for (int o = 8; o; o >>= 1) {
    #pragma unroll
    for (int r = 0; r < 4; ++r) {
      p0[r] += __shfl_xor(p0[r], o);
      p1[r] += __shfl_xor(p1[r], o);
    }
  }
  if (cg == 0) {
    #pragma unroll
    for (int r = 0; r < 4; ++r) {
      const int row = r0 + rg*4 + r;
      const float s0 = 1.f/(1.f + __expf(-(p0[r] + bf3[0])));
      const float s1 = 1.f/(1.f + __expf(-(p1[r] + bf3[1])));
      *(float2*)(out + row*2) = make_float2(s0, s1);
    }
  }
}

extern "C" void kernel_launch(void* const* d_in, const int* in_sizes, int n_in,
                              void* d_out, int out_size, void* d_ws, size_t ws_size,
                              hipStream_t stream) {
  (void)in_sizes; (void)n_in; (void)out_size; (void)ws_size;
  const float* x_ue      = (const float*)d_in[0];
  const float* x_ap      = (const float*)d_in[1];
  const float* edge_attr = (const float*)d_in[2];
  const int*   edge_src  = (const int*)d_in[3];
  const float* Wn1u = (const float*)d_in[5];
  const float* bn1u = (const float*)d_in[6];
  const float* Wn2u = (const float*)d_in[7];
  const float* bn2u = (const float*)d_in[8];
  const float* Wn1a = (const float*)d_in[9];
  const float* bn1a = (const float*)d_in[10];
  const float* Wn2a = (const float*)d_in[11];
  const float* bn2a = (const float*)d_in[12];
  const float* We1  = (const float*)d_in[13];
  const float* be1  = (const float*)d_in[14];
  const float* We2  = (const float*)d_in[15];
  const float* be2  = (const float*)d_in[16];
  const float* strong = (const float*)d_in[17];
  const float* inits  = (const float*)d_in[18];
  const float* update = (const float*)d_in[19];
  const float* Wu1  = (const float*)d_in[20];
  const float* bu1  = (const float*)d_in[21];
  const float* Wu2  = (const float*)d_in[22];
  const float* bu2  = (const float*)d_in[23];
  const float* ln_g = (const float*)d_in[24];
  const float* ln_b = (const float*)d_in[25];
  const float* Wf1  = (const float*)d_in[26];
  const float* bf1  = (const float*)d_in[27];
  const float* Wf2  = (const float*)d_in[28];
  const float* bf2  = (const float*)d_in[29];
  const float* Wf3  = (const float*)d_in[30];
  const float* bf3  = (const float*)d_in[31];

  float* ws = (float*)d_ws;

  enc_kernel<<<137, 256, 0, stream>>>(x_ue, x_ap, edge_attr,
                                      Wn1u, bn1u, Wn2u, bn2u,
                                      Wn1a, bn1a, Wn2a, bn2a,
                                      We1, be1, We2, be2,
                                      strong, inits, update, ws);
  circuit_kernel<<<2048, 256, 0, stream>>>(ws, edge_src,
                                           Wu1, bu1, Wu2, bu2, ln_g, ln_b);
  head_kernel<<<128, 256, 0, stream>>>(ws + G_F, Wf1, bf1, Wf2, bf2, Wf3, bf3,
                                       (float*)d_out);
}

// Round 15
// 35.078 us; speedup vs baseline: 1.0618x; 1.0618x over previous
//
#include <hip/hip_runtime.h>

#define LEAKY(x) ((x) > 0.0f ? (x) : 0.01f * (x))

// ws float layout
#define GP_F    672     // GP inside consts [0..2208)
#define APE     2208    // ap_enc 4096
#define UEE     6304    // ue_enc 16384
#define EAE     22688   // ea_enc 49152
#define G_F     71840   // g 16384

__device__ __forceinline__ float2 cmul(float2 a, float2 b) {
  return make_float2(fmaf(a.x, b.x, -a.y * b.y), fmaf(a.x, b.y, a.y * b.x));
}
__device__ __forceinline__ float2 cmulc(float2 a, float2 b) {  // conj(a)*b
  return make_float2(fmaf(a.x, b.x, a.y * b.y), fmaf(a.x, b.y, -a.y * b.x));
}
__device__ __forceinline__ float2 cadd(float2 a, float2 b) {
  return make_float2(a.x + b.x, a.y + b.y);
}
__device__ __forceinline__ float2 csub(float2 a, float2 b) {
  return make_float2(a.x - b.x, a.y - b.y);
}
__device__ __forceinline__ void swap2(float2& a, float2& b) {
  float2 t = a; a = b; b = t;
}

struct C2 { float2 e[4]; };

__device__ C2 cmm(const C2& A, const C2& B) {
  C2 R;
  #pragma unroll
  for (int r = 0; r < 2; ++r)
    #pragma unroll
    for (int c = 0; c < 2; ++c)
      R.e[r*2+c] = cadd(cmul(A.e[r*2+0], B.e[0*2+c]), cmul(A.e[r*2+1], B.e[1*2+c]));
  return R;
}
__device__ C2 gRX(float t) {
  float s = __sinf(0.5f*t), c = __cosf(0.5f*t);
  C2 M;
  M.e[0] = make_float2(c, 0.f);  M.e[1] = make_float2(0.f, -s);
  M.e[2] = make_float2(0.f, -s); M.e[3] = make_float2(c, 0.f);
  return M;
}
__device__ C2 gRY(float t) {
  float s = __sinf(0.5f*t), c = __cosf(0.5f*t);
  C2 M;
  M.e[0] = make_float2(c, 0.f);  M.e[1] = make_float2(-s, 0.f);
  M.e[2] = make_float2(s, 0.f);  M.e[3] = make_float2(c, 0.f);
  return M;
}
__device__ C2 gRZ(float t) {
  float s = __sinf(0.5f*t), c = __cosf(0.5f*t);
  C2 M;
  M.e[0] = make_float2(c, -s);    M.e[1] = make_float2(0.f, 0.f);
  M.e[2] = make_float2(0.f, 0.f); M.e[3] = make_float2(c, s);
  return M;
}
__device__ C2 gROT(float phi, float th, float om) {
  return cmm(cmm(gRZ(om), gRY(th)), gRZ(phi));
}

// row-per-thread 2-layer MLP; W1 transposed in LDS, all reads wave-uniform (broadcast).
template<int D>
__device__ __forceinline__ void encode_block(
    const float* __restrict__ x, int r,
    const float* __restrict__ W1, const float* __restrict__ b1,
    const float* __restrict__ W2, const float* __restrict__ b2,
    float* w1t, float* b1s, float* w2s, float* __restrict__ outp, int tid) {
  #pragma unroll
  for (int i = 0; i < D/2; ++i) {
    const int idx = i*256 + tid;
    const float v = W1[idx];
    w1t[(idx & 127)*D + (idx >> 7)] = v;
  }
  if (tid < 128) b1s[tid] = b1[tid];
  w2s[tid] = W2[tid];
  __syncthreads();

  float xv[D];
  *(float4*)xv = *(const float4*)(x + r*D);
  if (D == 8) *(float4*)(xv + 4) = *(const float4*)(x + r*D + 4);

  float o0 = 0.f, o1 = 0.f;
  #pragma unroll 4
  for (int j = 0; j < 128; ++j) {
    float h = b1s[j];
    #pragma unroll
    for (int k = 0; k < D; k += 4) {
      const float4 w = *(const float4*)&w1t[j*D + k];
      h = fmaf(xv[k],   w.x, h);
      h = fmaf(xv[k+1], w.y, h);
      h = fmaf(xv[k+2], w.z, h);
      h = fmaf(xv[k+3], w.w, h);
    }
    h = LEAKY(h);
    const float2 w2 = *(const float2*)&w2s[j*2];
    o0 = fmaf(h, w2.x, o0);
    o1 = fmaf(h, w2.y, o1);
  }
  *(float2*)(outp + r*2) = make_float2(o0 + b2[0], o1 + b2[1]);
}

// blocks 0..135: encoders (256 rows/block, row-per-thread). block 136: gate algebra.
__global__ __launch_bounds__(256) void enc_kernel(
    const float* __restrict__ x_ue, const float* __restrict__ x_ap,
    const float* __restrict__ edge_attr,
    const float* __restrict__ Wn1u, const float* __restrict__ bn1u,
    const float* __restrict__ Wn2u, const float* __restrict__ bn2u,
    const float* __restrict__ Wn1a, const float* __restrict__ bn1a,
    const float* __restrict__ Wn2a, const float* __restrict__ bn2a,
    const float* __restrict__ We1,  const float* __restrict__ be1,
    const float* __restrict__ We2,  const float* __restrict__ be2,
    const float* __restrict__ strongp, const float* __restrict__ initsp,
    const float* __restrict__ updatep, float* __restrict__ ws) {
  __shared__ __align__(16) float w1t[1024];
  __shared__ float b1s[128];
  __shared__ __align__(8) float w2s[256];
  __shared__ float2 U2s[16][17];
  const int bi = blockIdx.x, tid = threadIdx.x;

  if (bi < 32) {
    encode_block<8>(x_ue, bi*256 + tid, Wn1u, bn1u, Wn2u, bn2u,
                    w1t, b1s, w2s, ws + UEE, tid);
    return;
  } else if (bi < 40) {
    encode_block<8>(x_ap, (bi-32)*256 + tid, Wn1a, bn1a, Wn2a, bn2a,
                    w1t, b1s, w2s, ws + APE, tid);
    return;
  } else if (bi < 136) {
    encode_block<4>(edge_attr, (bi-40)*256 + tid, We1, be1, We2, be2,
                    w1t, b1s, w2s, ws + EAE, tid);
    return;
  }

  // ---- gate algebra (block 136) ----
  if (tid < 48) {
    // U_k (k=tid>>4), column col=tid&15. bit masks: wire3=8, nb=4, w7=2, w8=1.
    const int k = tid >> 4, col = tid & 15;
    float2 u[16];
    #pragma unroll
    for (int r = 0; r < 16; ++r) u[r] = make_float2(r == col ? 1.f : 0.f, 0.f);
    #pragma unroll
    for (int l = 0; l < 2; ++l) {
      #pragma unroll
      for (int j = 0; j < 4; ++j) {
        const float* p = updatep + k*24 + l*12 + j*3;
        C2 U = gROT(p[0], p[1], p[2]);
        const int m = 8 >> j;
        #pragma unroll
        for (int r = 0; r < 16; ++r)
          if (!(r & m)) {
            float2 a0 = u[r], a1 = u[r | m];
            u[r]     = cadd(cmul(U.e[0], a0), cmul(U.e[1], a1));
            u[r | m] = cadd(cmul(U.e[2], a0), cmul(U.e[3], a1));
          }
      }
      #pragma unroll
      for (int j = 0; j < 4; ++j) {
        const int mc = 8 >> j;
        const int mt0[4] = {4, 2, 1, 8};
        const int mt1[4] = {2, 1, 8, 4};
        const int mt = (l == 0) ? mt0[j] : mt1[j];
        #pragma unroll
        for (int r = 0; r < 16; ++r)
          if ((r & mc) && !(r & mt)) swap2(u[r], u[r | mt]);
      }
    }
    if (k == 0) {
      if (!(col & 3)) {
        const int jc = col >> 2;
        #pragma unroll
        for (int r = 0; r < 16; ++r) {
          ws[32 + (jc*16 + r)*2 + 0] = u[r].x;
          ws[32 + (jc*16 + r)*2 + 1] = u[r].y;
        }
      }
    } else if (k == 1) {
      // paired layout: U1tp[col][rp] = (U1[r][col], U1[r+4][col]), r = (rp&3)|((rp&4)<<1)
      #pragma unroll
      for (int rp = 0; rp < 8; ++rp) {
        const int r = (rp & 3) | ((rp & 4) << 1);
        ws[160 + (col*8 + rp)*4 + 0] = u[r].x;
        ws[160 + (col*8 + rp)*4 + 1] = u[r].y;
        ws[160 + (col*8 + rp)*4 + 2] = u[r+4].x;
        ws[160 + (col*8 + rp)*4 + 3] = u[r+4].y;
      }
    } else {
      #pragma unroll
      for (int r = 0; r < 16; ++r) U2s[col][r] = u[r];   // U2s[q][t] = U2[t][q]
    }
  }
  if (tid == 48) {
    // M_edge 4x4 (basis (b_e<<1)|b_nb)
    float2 M[4][4];
    #pragma unroll
    for (int r = 0; r < 4; ++r)
      #pragma unroll
      for (int c = 0; c < 4; ++c)
        M[r][c] = make_float2(r == c ? 1.f : 0.f, 0.f);
    auto rowpair = [&](int r0, int r1, C2 U) {
      #pragma unroll
      for (int c = 0; c < 4; ++c) {
        float2 a0 = M[r0][c], a1 = M[r1][c];
        M[r0][c] = cadd(cmul(U.e[0], a0), cmul(U.e[1], a1));
        M[r1][c] = cadd(cmul(U.e[2], a0), cmul(U.e[3], a1));
      }
    };
    auto rowswap = [&](int r0, int r1) {
      #pragma unroll
      for (int c = 0; c < 4; ++c) swap2(M[r0][c], M[r1][c]);
    };
    rowpair(1, 3, gRX(initsp[0]));
    rowpair(2, 3, gRY(initsp[1]));
    #pragma unroll
    for (int l = 0; l < 2; ++l) {
      C2 Re = gROT(strongp[l*6+0], strongp[l*6+1], strongp[l*6+2]);
      C2 Rn = gROT(strongp[l*6+3], strongp[l*6+4], strongp[l*6+5]);
      rowpair(0, 2, Re); rowpair(1, 3, Re);
      rowpair(0, 1, Rn); rowpair(2, 3, Rn);
      rowswap(2, 3);
      rowswap(1, 3);
    }
    #pragma unroll
    for (int r = 0; r < 4; ++r)
      #pragma unroll
      for (int c = 0; c < 4; ++c) {
        ws[(r*4 + c)*2 + 0] = M[r][c].x;
        ws[(r*4 + c)*2 + 1] = M[r][c].y;
      }
  }
  __syncthreads();
  {
    // GP: 256 threads, one (c,cp,n,np) each, 3 wires.
    const int c = tid >> 5, cp = (tid >> 2) & 7, n = (tid >> 1) & 1, np = tid & 1;
    const int q  = ((c  & 4) << 1) | (n  << 2) | (c  & 3);
    const int qp = ((cp & 4) << 1) | (np << 2) | (cp & 3);
    float2 g3 = make_float2(0,0), g7 = g3, g8 = g3;
    #pragma unroll
    for (int t = 0; t < 16; ++t) {
      float2 pr = cmulc(U2s[q][t], U2s[qp][t]);
      g3 = (t & 8) ? csub(g3, pr) : cadd(g3, pr);
      g7 = (t & 2) ? csub(g7, pr) : cadd(g7, pr);
      g8 = (t & 1) ? csub(g8, pr) : cadd(g8, pr);
    }
    const int idx = (c*2 + n)*16 + (cp*2 + np);
    ws[GP_F + (0*256 + idx)*2 + 0] = g3.x;
    ws[GP_F + (0*256 + idx)*2 + 1] = g3.y;
    ws[GP_F + (1*256 + idx)*2 + 0] = g7.x;
    ws[GP_F + (1*256 + idx)*2 + 1] = g7.y;
    ws[GP_F + (2*256 + idx)*2 + 0] = g8.x;
    ws[GP_F + (2*256 + idx)*2 + 1] = g8.y;
  }
}

// 4 UEs/block (1/wave). Consts read straight from global (L1-resident); no barrier.
__global__ __launch_bounds__(256) void circuit_kernel(
    float* __restrict__ ws, const int* __restrict__ esrc,
    const float* __restrict__ Wu1, const float* __restrict__ bu1,
    const float* __restrict__ Wu2, const float* __restrict__ bu2,
    const float* __restrict__ lng, const float* __restrict__ lnb) {
  __shared__ __align__(16) float2 pr_s[4][3][4];
  __shared__ __align__(16) float2 psi0[4][2][16];
  __shared__ __align__(16) float4 psi2p[4][8][8];  // [wv][ibr][rp] = (z[r], z[r+4])
  const int tid = threadIdx.x, wv = tid >> 6, lane = tid & 63;
  const int u = blockIdx.x*4 + wv;

  // ---- prefetch per-UE inputs + Wu weights (lane-only deps; hide latency) ----
  const float2 ue_ab = *(const float2*)(ws + UEE + u*2);
  float2 eab_r = make_float2(0.f, 0.f), nab_r = make_float2(0.f, 0.f);
  if (lane < 12) {
    const int i = lane >> 2;
    eab_r = *(const float2*)(ws + EAE + (u*3 + i)*2);
    const int s = esrc[u*3 + i];
    nab_r = *(const float2*)(ws + APE + s*2);
  }
  const int j1 = lane, j2 = lane + 64;
  float wu_a[5], wu_b[5];
  #pragma unroll
  for (int k = 0; k < 5; ++k) {
    wu_a[k] = Wu1[k*128 + j1];
    wu_b[k] = Wu1[k*128 + j2];
  }
  const float bu1a = bu1[j1], bu1b = bu1[j2];
  const float2 wu2a = *(const float2*)(Wu2 + j1*2);
  const float2 wu2b = *(const float2*)(Wu2 + j2*2);

  const float2* MEg  = (const float2*)ws;            // 16
  const float2* U0cg = (const float2*)ws + 16;       // 64  [j][r]
  const float4* U1tg = (const float4*)(ws + 160);    // 128 [q][rp] paired
  const float4* GP4g = (const float4*)(ws + GP_F);   // paired GP

  auto mkv = [](float aa, float bb, float2& v0, float2& v1) {
    const float sa = __sinf(0.5f*aa), ca = __cosf(0.5f*aa);
    const float sb = __sinf(0.5f*bb), cb = __cosf(0.5f*bb);
    v0 = make_float2(cb*ca, -sb*ca);
    v1 = make_float2(sa*sb, -sa*cb);
  };
  float2 t0, t1;
  mkv(ue_ab.x, ue_ab.y, t0, t1);

  // ---- pairs (lanes 0..11): i = lane>>2, r = lane&3 ----
  if (lane < 12) {
    const int r = lane & 3;
    float2 e0, e1, n0, n1;
    mkv(eab_r.x, eab_r.y, e0, e1);
    mkv(nab_r.x, nab_r.y, n0, n1);
    float2 in4[4] = {cmul(e0,n0), cmul(e0,n1), cmul(e1,n0), cmul(e1,n1)};
    float2 acc = make_float2(0.f, 0.f);
    #pragma unroll
    for (int cc = 0; cc < 4; ++cc) acc = cadd(acc, cmul(MEg[r*4 + cc], in4[cc]));
    pr_s[wv][lane >> 2][r] = acc;
  }

  // ---- block0: psi0 (lanes 0..31) ----
  if (lane < 32) {
    const int b = lane >> 4, row = lane & 15;
    float2 acc = make_float2(0.f, 0.f);
    #pragma unroll
    for (int j = 0; j < 4; ++j) {
      const float2 phi = pr_s[wv][0][(b << 1) | (j & 1)];
      const float2 coef = cmul((j >> 1) ? t1 : t0, phi);
      acc = cadd(acc, cmul(U0cg[j*16 + row], coef));
    }
    psi0[wv][b][row] = acc;
  }

  // ---- block1: psi2 (all lanes, rows (r, r+4) per lane) ----
  {
    const int ibr = lane >> 3, rp = lane & 7;
    const int db = ibr >> 2, da = (ibr >> 1) & 1, dbp = ibr & 1;
    const float2 f10 = pr_s[wv][1][(dbp << 1) | 0];
    const float2 f11 = pr_s[wv][1][(dbp << 1) | 1];
    float2 chi[8];
    {
      const float4 a0 = *(const float4*)&psi0[wv][db][da*4 + 0];
      const float4 a1 = *(const float4*)&psi0[wv][db][da*4 + 2];
      const float4 a2 = *(const float4*)&psi0[wv][db][8 + da*4 + 0];
      const float4 a3 = *(const float4*)&psi0[wv][db][8 + da*4 + 2];
      chi[0] = make_float2(a0.x, a0.y); chi[1] = make_float2(a0.z, a0.w);
      chi[2] = make_float2(a1.x, a1.y); chi[3] = make_float2(a1.z, a1.w);
      chi[4] = make_float2(a2.x, a2.y); chi[5] = make_float2(a2.z, a2.w);
      chi[6] = make_float2(a3.x, a3.y); chi[7] = make_float2(a3.z, a3.w);
    }
    float2 q0 = make_float2(0.f, 0.f), q1 = q0;
    #pragma unroll
    for (int q = 0; q < 16; ++q) {
      const int cc = ((q >> 3) << 2) | (q & 3);
      const float2 xq = cmul(chi[cc], (q & 4) ? f11 : f10);
      const float4 uf = U1tg[q*8 + rp];
      const float2 u_lo = make_float2(uf.x, uf.y);
      const float2 u_hi = make_float2(uf.z, uf.w);
      q0 = cadd(q0, cmul(u_lo, xq));
      q1 = cadd(q1, cmul(u_hi, xq));
    }
    psi2p[wv][ibr][rp] = make_float4(q0.x, q0.y, q1.x, q1.y);
  }

  // ---- R[c,cp] ----
  const int c = lane >> 3, cp = lane & 7;
  float2 R = make_float2(0.f, 0.f);
  #pragma unroll
  for (int br = 0; br < 8; ++br) {
    const float4 Z1 = psi2p[wv][br][c];
    const float4 Z2 = psi2p[wv][br][cp];
    R.x += Z1.x*Z2.x + Z1.y*Z2.y + Z1.z*Z2.z + Z1.w*Z2.w;
    R.y += Z1.y*Z2.x - Z1.x*Z2.y + Z1.w*Z2.z - Z1.z*Z2.w;
  }

  // ---- rho2, K_w, ev ----
  const float4 f2a = *(const float4*)&pr_s[wv][2][0];
  const float4 f2b = *(const float4*)&pr_s[wv][2][2];
  const float2 f20 = make_float2(f2a.x, f2a.y), f21 = make_float2(f2a.z, f2a.w);
  const float2 f22 = make_float2(f2b.x, f2b.y), f23 = make_float2(f2b.z, f2b.w);
  const float2 rho00 = make_float2(f20.x*f20.x + f20.y*f20.y + f22.x*f22.x + f22.y*f22.y, 0.f);
  const float2 rho11 = make_float2(f21.x*f21.x + f21.y*f21.y + f23.x*f23.x + f23.y*f23.y, 0.f);
  const float2 rho01 = make_float2(fmaf(f20.x,f21.x,f20.y*f21.y) + fmaf(f22.x,f23.x,f22.y*f23.y),
                                   (f20.y*f21.x - f20.x*f21.y) + (f22.y*f23.x - f22.x*f23.y));
  const float2 rho10 = make_float2(rho01.x, -rho01.y);

  float ev0, ev1, ev2;
  {
    const int base4 = c*16 + cp;   // float4 index
    #pragma unroll
    for (int w = 0; w < 3; ++w) {
      const float4 Ga = GP4g[w*128 + base4];       // (g00, g01)
      const float4 Gb = GP4g[w*128 + base4 + 8];   // (g10, g11)
      const float2 g00 = make_float2(Ga.x, Ga.y), g01 = make_float2(Ga.z, Ga.w);
      const float2 g10 = make_float2(Gb.x, Gb.y), g11 = make_float2(Gb.z, Gb.w);
      float2 K = cmul(g00, rho00);
      K = cadd(K, cmul(g01, rho10));
      K = cadd(K, cmul(g10, rho01));
      K = cadd(K, cmul(g11, rho11));
      const float e = K.x*R.x + K.y*R.y;
      if (w == 0) ev0 = e; else if (w == 1) ev1 = e; else ev2 = e;
    }
  }
  #pragma unroll
  for (int o = 32; o; o >>= 1) {
    ev0 += __shfl_xor(ev0, o);
    ev1 += __shfl_xor(ev1, o);
    ev2 += __shfl_xor(ev2, o);
  }

  // ---- Wu MLP + residual + LN -> g (weights preloaded) ----
  const float in5[5] = {ue_ab.x, ue_ab.y, ev0, ev1, ev2};
  float h1 = bu1a, h2 = bu1b;
  #pragma unroll
  for (int k = 0; k < 5; ++k) {
    h1 = fmaf(in5[k], wu_a[k], h1);
    h2 = fmaf(in5[k], wu_b[k], h2);
  }
  h1 = LEAKY(h1); h2 = LEAKY(h2);
  float p0 = fmaf(h1, wu2a.x, h2*wu2b.x);
  float p1 = fmaf(h1, wu2a.y, h2*wu2b.y);
  #pragma unroll
  for (int o = 32; o; o >>= 1) { p0 += __shfl_xor(p0, o); p1 += __shfl_xor(p1, o); }
  if (lane == 0) {
    const float hh0 = ue_ab.x + p0 + bu2[0];
    const float hh1 = ue_ab.y + p1 + bu2[1];
    const float mu = 0.5f*(hh0 + hh1);
    const float dd = hh0 - mu;
    const float inv = rsqrtf(dd*dd + 1e-5f);
    const float g0 =  dd*inv*lng[0] + lnb[0];
    const float g1 = -dd*inv*lng[1] + lnb[1];
    *(float2*)(ws + G_F + u*2) = make_float2(g0, g1);
  }
}

// head GEMM: 32 rows/block (256 blocks -> full chip), thread tile 2 rows x 8 cols.
__global__ __launch_bounds__(256) void head_kernel(
    const float* __restrict__ g,
    const float* __restrict__ Wf1, const float* __restrict__ bf1,
    const float* __restrict__ Wf2, const float* __restrict__ bf2,
    const float* __restrict__ Wf3, const float* __restrict__ bf3,
    float* __restrict__ out) {
  __shared__ __align__(16) float act_t[128][32];   // [j][row], 16 KB
  const int tid = threadIdx.x;
  const int r0 = blockIdx.x * 32;

  // ---- phase 1: act_t[j][row] = leaky(g@Wf1 + bf1); 8 threads/row, 16 j each
  {
    const int row = tid & 31, jg = tid >> 5;
    const float2 gv = *(const float2*)(g + (r0 + row)*2);
    #pragma unroll
    for (int p = 0; p < 16; ++p) {
      const int j = p*8 + jg;
      act_t[j][row] = LEAKY(fmaf(gv.x, Wf1[j], fmaf(gv.y, Wf1[128 + j], bf1[j])));
    }
  }
  __syncthreads();

  // ---- phase 2: GEMM. cg = tid&15 (8 cols each), rg = tid>>4 (2 rows each).
  const int cg = tid & 15, rg = tid >> 4;
  float acc[2][8];
  {
    const float4 b0 = *(const float4*)(bf2 + cg*8);
    const float4 b1 = *(const float4*)(bf2 + cg*8 + 4);
    #pragma unroll
    for (int r = 0; r < 2; ++r) {
      acc[r][0]=b0.x; acc[r][1]=b0.y; acc[r][2]=b0.z; acc[r][3]=b0.w;
      acc[r][4]=b1.x; acc[r][5]=b1.y; acc[r][6]=b1.z; acc[r][7]=b1.w;
    }
  }
  #pragma unroll 4
  for (int k = 0; k < 128; ++k) {
    const float2 a2 = *(const float2*)&act_t[k][rg*2];
    const float4 w0 = *(const float4*)(Wf2 + k*128 + cg*8);
    const float4 w1 = *(const float4*)(Wf2 + k*128 + cg*8 + 4);
    const float av[2] = {a2.x, a2.y};
    #pragma unroll
    for (int r = 0; r < 2; ++r) {
      acc[r][0] = fmaf(av[r], w0.x, acc[r][0]);
      acc[r][1] = fmaf(av[r], w0.y, acc[r][1]);
      acc[r][2] = fmaf(av[r], w0.z, acc[r][2]);
      acc[r][3] = fmaf(av[r], w0.w, acc[r][3]);
      acc[r][4] = fmaf(av[r], w1.x, acc[r][4]);
      acc[r][5] = fmaf(av[r], w1.y, acc[r][5]);
      acc[r][6] = fmaf(av[r], w1.z, acc[r][6]);
      acc[r][7] = fmaf(av[r], w1.w, acc[r][7]);
    }
  }

  // ---- epilogue: leaky, @Wf3, reduce over cg, sigmoid
  float w3x[8], w3y[8];
  #pragma unroll
  for (int c = 0; c < 8; ++c) {
    const float2 w3 = *(const float2*)(Wf3 + (cg*8 + c)*2);
    w3x[c] = w3.x; w3y[c] = w3.y;
  }
  float p0[2], p1[2];
  #pragma unroll
  for (int r = 0; r < 2; ++r) {
    float s0 = 0.f, s1 = 0.f;
    #pragma unroll
    for (int c = 0; c < 8; ++c) {
      const float v = LEAKY(acc[r][c]);
      s0 = fmaf(v, w3x[c], s0);
      s1 = fmaf(v, w3y[c], s1);
    }
    p0[r] = s0; p1[r] = s1;
  }
  #pragma unroll
  for (int o = 8; o; o >>= 1) {
    #pragma unroll
    for (int r = 0; r < 2; ++r) {
      p0[r] += __shfl_xor(p0[r], o);
      p1[r] += __shfl_xor(p1[r], o);
    }
  }
  if (cg == 0) {
    #pragma unroll
    for (int r = 0; r < 2; ++r) {
      const int row = r0 + rg*2 + r;
      const float s0 = 1.f/(1.f + __expf(-(p0[r] + bf3[0])));
      const float s1 = 1.f/(1.f + __expf(-(p1[r] + bf3[1])));
      *(float2*)(out + row*2) = make_float2(s0, s1);
    }
  }
}

extern "C" void kernel_launch(void* const* d_in, const int* in_sizes, int n_in,
                              void* d_out, int out_size, void* d_ws, size_t ws_size,
                              hipStream_t stream) {
  (void)in_sizes; (void)n_in; (void)out_size; (void)ws_size;
  const float* x_ue      = (const float*)d_in[0];
  const float* x_ap      = (const float*)d_in[1];
  const float* edge_attr = (const float*)d_in[2];
  const int*   edge_src  = (const int*)d_in[3];
  const float* Wn1u = (const float*)d_in[5];
  const float* bn1u = (const float*)d_in[6];
  const float* Wn2u = (const float*)d_in[7];
  const float* bn2u = (const float*)d_in[8];
  const float* Wn1a = (const float*)d_in[9];
  const float* bn1a = (const float*)d_in[10];
  const float* Wn2a = (const float*)d_in[11];
  const float* bn2a = (const float*)d_in[12];
  const float* We1  = (const float*)d_in[13];
  const float* be1  = (const float*)d_in[14];
  const float* We2  = (const float*)d_in[15];
  const float* be2  = (const float*)d_in[16];
  const float* strong = (const float*)d_in[17];
  const float* inits  = (const float*)d_in[18];
  const float* update = (const float*)d_in[19];
  const float* Wu1  = (const float*)d_in[20];
  const float* bu1  = (const float*)d_in[21];
  const float* Wu2  = (const float*)d_in[22];
  const float* bu2  = (const float*)d_in[23];
  const float* ln_g = (const float*)d_in[24];
  const float* ln_b = (const float*)d_in[25];
  const float* Wf1  = (const float*)d_in[26];
  const float* bf1  = (const float*)d_in[27];
  const float* Wf2  = (const float*)d_in[28];
  const float* bf2  = (const float*)d_in[29];
  const float* Wf3  = (const float*)d_in[30];
  const float* bf3  = (const float*)d_in[31];

  float* ws = (float*)d_ws;

  enc_kernel<<<137, 256, 0, stream>>>(x_ue, x_ap, edge_attr,
                                      Wn1u, bn1u, Wn2u, bn2u,
                                      Wn1a, bn1a, Wn2a, bn2a,
                                      We1, be1, We2, be2,
                                      strong, inits, update, ws);
  circuit_kernel<<<2048, 256, 0, stream>>>(ws, edge_src,
                                           Wu1, bu1, Wu2, bu2, ln_g, ln_b);
  head_kernel<<<256, 256, 0, stream>>>(ws + G_F, Wf1, bf1, Wf2, bf2, Wf3, bf3,
                                       (float*)d_out);
}